// Round 5
// baseline (681.651 us; speedup 1.0000x reference)
//
#include <hip/hip_runtime.h>
#include <hip/hip_cooperative_groups.h>
#include <cstdint>
#include <cstddef>

namespace cg = cooperative_groups;

#define NB 4
#define NG 8
#define NCELL 331776   // 48*48*48*3
#define NTILE 1296     // 256-cell tiles per batch
#define TOTCHUNK (NTILE * NB)   // 5184
#define NBLK 1296
#define KTOP 800
#define NREP 8         // global histogram replicas to spread atomic traffic
#define CAP 16384      // per-batch candidate buffer capacity (expected ~7.4k)
#define LCAP 8192      // candidates cached in LDS when m <= LCAP (32 KB)
#define GRID 1024      // cooperative grid: 4 blocks/CU x 256 CUs

struct WsHeader {
  float pos_sum[NB];
  float reg_sum[NB];
  int   npos[NB];
  int   neg_cnt[NB];
  int   take_all[NB];
  int   prefix8[NB];            // top-byte threshold bucket j
  int   k_rem[NB];              // KTOP - count(top byte > j)
  float neg_sum[NB];
  int   done;
  int   bucket_cnt[NB][16];     // one cacheline per batch
  unsigned int hist[NB][NREP][256];
};

__device__ __forceinline__ float softplus0(float x) {
  return fmaxf(x, 0.f) + log1pf(expf(-fabsf(x)));
}
__device__ __forceinline__ unsigned int f2key(float f) {
  unsigned int u = __float_as_uint(f);
  return (u & 0x80000000u) ? ~u : (u | 0x80000000u);
}
__device__ __forceinline__ float key2f(unsigned int k) {
  unsigned int u = (k & 0x80000000u) ? (k & 0x7fffffffu) : ~k;
  return __uint_as_float(u);
}
__device__ __forceinline__ float sl1(float x) {
  float ax = fabsf(x);
  return ax < 1.f ? 0.5f * x * x : ax - 0.5f;
}

// ---------------- fused cooperative kernel ----------------
// LDS carve (8728 words = 34912 B -> 4 blocks/CU):
//  phase1: ld[1280]f @0, gts[128]f @1280, lhist[2][NB][256] @1408..3455
//  phase2: A[256] @0, cnts[256] @256
//  phase3: skeys[8192] @0, h[256] @8192, A[256] @8448, wred[16]f @8704
//  scalars @8720..8727
__global__ __launch_bounds__(256, 4) void fused_kernel(const float* __restrict__ pred,
                                                       const float* __restrict__ tgt,
                                                       WsHeader* __restrict__ ws,
                                                       unsigned int* __restrict__ keys,
                                                       unsigned int* __restrict__ bucket,
                                                       float* __restrict__ out) {
  cg::grid_group grid = cg::this_grid();
  const int tid = threadIdx.x;
  const int bid = blockIdx.x;
  __shared__ __align__(16) unsigned int smem[8728];

  // ---- phase 0: zero workspace header ----
  {
    unsigned int* p = (unsigned int*)ws;
    const int nw = (int)(sizeof(WsHeader) / 4);
    for (int i = bid * 256 + tid; i < nw; i += GRID * 256) p[i] = 0u;
  }
  __threadfence();
  grid.sync();

  // ---- phase 1: per-cell loss terms + key write + histogram ----
  {
    float* ld  = (float*)smem;            // 1280 floats
    float* gts = (float*)(smem + 1280);   // 128 floats
    unsigned int* lhist = smem + 1408;    // 2048 words
    float* s_psum = (float*)(smem + 8720);
    float* s_rsum = (float*)(smem + 8721);
    int*   s_np   = (int*)(smem + 8722);

    if (tid < NB * NG * 4) gts[tid] = tgt[tid];
    for (int e = tid; e < 2048; e += 256) lhist[e] = 0u;

    for (int c = bid; c < TOTCHUNK; c += GRID) {
      const int b = c / NTILE;
      const int tile = c - b * NTILE;
      __syncthreads();                    // prev iter fully consumed
      if (tid == 0) { *s_psum = 0.f; *s_rsum = 0.f; *s_np = 0; }
      // coalesced stage: 256 cells x 5 floats = 320 float4
      const float4* p4 = (const float4*)(pred + ((size_t)b * NCELL + (size_t)tile * 256) * 5);
      float4* ld4 = (float4*)ld;
      ld4[tid] = p4[tid];
      if (tid < 64) ld4[256 + tid] = p4[256 + tid];
      __syncthreads();

      const int i = tile * 256 + tid;
      int a = i % 3; int t = i / 3;
      int w = t % 48; t /= 48;
      int h = t % 48; int d = t / 48;
      const float cx = w * 4.f + 2.f, cy = h * 4.f + 2.f, cz = d * 4.f + 2.f;
      const float anch[3] = {5.f, 10.f, 20.f};
      const float an = anch[a];
      const float r1 = an * 0.5f;
      const float an3 = an * an * an;
      const float* gt = gts + b * NG * 4;

      float best = -1.f; int arg = 0;
#pragma unroll
      for (int g = 0; g < NG; ++g) {
        float gx = gt[g * 4 + 0], gy = gt[g * 4 + 1], gz = gt[g * 4 + 2], gd = gt[g * 4 + 3];
        float r2 = gd * 0.5f;
        float ix = fmaxf(fminf(cx + r1, gx + r2) - fmaxf(cx - r1, gx - r2), 0.f);
        float iy = fmaxf(fminf(cy + r1, gy + r2) - fmaxf(cy - r1, gy - r2), 0.f);
        float iz = fmaxf(fminf(cz + r1, gz + r2) - fmaxf(cz - r1, gz - r2), 0.f);
        float iv = (ix * iy) * iz;
        float un = (an3 + gd * gd * gd) - iv;
        float iou = iv / (un + 1e-6f);
        if (iou > best) { best = iou; arg = g; }   // strict > == first-argmax
      }
      const bool pos = best > 0.5f;
      const bool neg = best < 0.02f;
      const float conf = ld[tid * 5];

      unsigned int key = 0u;   // sentinel: -NaN bits, unreachable
      if (neg) {
        key = f2key(conf);
        atomicAdd(&lhist[(((tid & 1) * NB + b) << 8) | (key >> 24)], 1u);
      }
      keys[(size_t)b * NCELL + i] = key;

      if (pos) {
        float bce1 = fmaxf(conf, 0.f) - conf + log1pf(expf(-fabsf(conf)));
        float mgx = gt[arg * 4 + 0], mgy = gt[arg * 4 + 1], mgz = gt[arg * 4 + 2], mgd = gt[arg * 4 + 3];
        float t0 = (mgx - cx) / an, t1 = (mgy - cy) / an, t2 = (mgz - cz) / an;
        float t3 = logf(mgd / an);
        float d0 = ld[tid * 5 + 1] - t0;
        float d1 = ld[tid * 5 + 2] - t1;
        float d2 = ld[tid * 5 + 3] - t2;
        float d3 = ld[tid * 5 + 4] - t3;
        float rl = sl1(d0) + sl1(d1) + sl1(d2) + sl1(d3);
        atomicAdd(s_psum, bce1);
        atomicAdd(s_rsum, rl);
        atomicAdd(s_np, 1);
      }
      __syncthreads();
      if (tid == 0 && *s_np > 0) {
        atomicAdd(&ws->pos_sum[b], *s_psum);
        atomicAdd(&ws->reg_sum[b], *s_rsum);
        atomicAdd(&ws->npos[b], *s_np);
      }
    }
    __syncthreads();
    // flush block-local histogram into global replicas
    for (int e = tid; e < NB * 256; e += 256) {
      int b2 = e >> 8, bin = e & 255;
      unsigned int v = lhist[((0 * NB + b2) << 8) | bin] + lhist[((1 * NB + b2) << 8) | bin];
      if (v) atomicAdd(&ws->hist[b2][bid & (NREP - 1)][bin], v);
    }
  }
  __threadfence();
  grid.sync();

  // ---- phase 2: threshold bucket + compaction (blocks 0..323) ----
  if (bid < NB * 81) {
    unsigned int* A    = smem;
    unsigned int* cnts = smem + 256;
    int* sh_j    = (int*)(smem + 8723);
    int* sh_base = (int*)(smem + 8724);
    const int b = bid / 81;
    const int tl = bid - b * 81;

    unsigned int s = 0;
#pragma unroll
    for (int r = 0; r < NREP; ++r) s += ws->hist[b][r][tid];
    A[tid] = s;
    __syncthreads();
    for (int dlt = 1; dlt < 256; dlt <<= 1) {     // suffix scan
      unsigned int v = (tid + dlt < 256) ? A[tid + dlt] : 0u;
      __syncthreads();
      A[tid] += v;
      __syncthreads();
    }
    const int M = (int)A[0];
    const bool ta = (M < KTOP);
    if (!ta && A[tid] >= (unsigned)KTOP && (tid == 255 || A[tid + 1] < (unsigned)KTOP))
      *sh_j = tid;
    __syncthreads();
    const unsigned int jthr = ta ? 0u : (unsigned int)*sh_j;
    if (tid == 0 && tl == 0) {
      ws->neg_cnt[b] = M;
      ws->take_all[b] = ta ? 1 : 0;
      ws->prefix8[b] = (int)jthr;
      int above = (!ta && jthr < 255u) ? (int)A[jthr + 1] : 0;
      ws->k_rem[b] = ta ? 0 : (KTOP - above);
    }

    const uint4* k4 = (const uint4*)(keys + (size_t)b * NCELL);
    const int base4 = tl * 1024;
    int cnt = 0;
#pragma unroll
    for (int it = 0; it < 4; ++it) {
      uint4 kk = k4[base4 + it * 256 + tid];
      cnt += (kk.x != 0u && (kk.x >> 24) >= jthr);
      cnt += (kk.y != 0u && (kk.y >> 24) >= jthr);
      cnt += (kk.z != 0u && (kk.z >> 24) >= jthr);
      cnt += (kk.w != 0u && (kk.w >> 24) >= jthr);
    }
    cnts[tid] = (unsigned int)cnt;
    __syncthreads();
    for (int dlt = 1; dlt < 256; dlt <<= 1) {     // prefix scan
      unsigned int v = (tid >= dlt) ? cnts[tid - dlt] : 0u;
      __syncthreads();
      cnts[tid] += v;
      __syncthreads();
    }
    if (tid == 255) {
      int total = (int)cnts[255];
      *sh_base = total ? atomicAdd(&ws->bucket_cnt[b][0], total) : 0;
    }
    __syncthreads();
    int off = *sh_base + (int)cnts[tid] - cnt;
#pragma unroll
    for (int it = 0; it < 4; ++it) {
      uint4 kk = k4[base4 + it * 256 + tid];
      unsigned int kv;
      kv = kk.x; if (kv != 0u && (kv >> 24) >= jthr) { if (off < CAP) bucket[(size_t)b * CAP + off] = kv; ++off; }
      kv = kk.y; if (kv != 0u && (kv >> 24) >= jthr) { if (off < CAP) bucket[(size_t)b * CAP + off] = kv; ++off; }
      kv = kk.z; if (kv != 0u && (kv >> 24) >= jthr) { if (off < CAP) bucket[(size_t)b * CAP + off] = kv; ++off; }
      kv = kk.w; if (kv != 0u && (kv >> 24) >= jthr) { if (off < CAP) bucket[(size_t)b * CAP + off] = kv; ++off; }
    }
  }
  __threadfence();
  grid.sync();

  // ---- phase 3: exact top-K select + sums + combine (blocks 0..3) ----
  if (bid >= NB) return;
  {
    const int b = bid;
    unsigned int* skeys = smem;            // 8192
    unsigned int* h  = smem + 8192;
    unsigned int* A  = smem + 8448;
    float* wred      = (float*)(smem + 8704);  // 16
    int* sh_j   = (int*)(smem + 8723);
    int* sh_last = (int*)(smem + 8725);

    int m = ws->bucket_cnt[b][0]; if (m > CAP) m = CAP;
    const bool ta = ws->take_all[b] != 0;
    const unsigned int* kb = bucket + (size_t)b * CAP;
    const bool useLds = (m <= LCAP);
    if (useLds)
      for (int i = tid; i < m; i += 256) skeys[i] = kb[i];
    __syncthreads();

    unsigned int T = 0u;
    int k = 0;
    if (!ta) {
      unsigned int P = ((unsigned int)ws->prefix8[b]) << 24;
      k = ws->k_rem[b];
      for (int pass = 1; pass < 4; ++pass) {
        const int sh = 24 - 8 * pass;
        const unsigned int hiMask = 0xFFFFFFFFu << (sh + 8);
        h[tid] = 0u;
        __syncthreads();
        for (int i = tid; i < m; i += 256) {
          unsigned int kv = useLds ? skeys[i] : kb[i];
          if (((kv ^ P) & hiMask) == 0u) atomicAdd(&h[(kv >> sh) & 255u], 1u);
        }
        __syncthreads();
        A[tid] = h[tid];
        __syncthreads();
        for (int dlt = 1; dlt < 256; dlt <<= 1) {
          unsigned int v = (tid + dlt < 256) ? A[tid + dlt] : 0u;
          __syncthreads();
          A[tid] += v;
          __syncthreads();
        }
        if (A[tid] >= (unsigned)k && (tid == 255 || A[tid + 1] < (unsigned)k))
          *sh_j = tid;
        __syncthreads();
        const int j = *sh_j;
        k -= (j == 255) ? 0 : (int)A[j + 1];
        P |= ((unsigned int)j) << sh;
        __syncthreads();
      }
      T = P;
    }

    float v = 0.f;
    for (int i = tid; i < m; i += 256) {
      unsigned int kv = useLds ? skeys[i] : kb[i];
      if (ta || kv > T) v += softplus0(key2f(kv));
    }
    for (int o = 32; o > 0; o >>= 1) v += __shfl_down(v, o);
    if ((tid & 63) == 0) wred[tid >> 6] = v;
    __syncthreads();
    if (tid == 0) {
      float sum = wred[0] + wred[1] + wred[2] + wred[3];
      if (!ta) sum += (float)k * softplus0(key2f(T));
      ws->neg_sum[b] = sum;
      __threadfence();
      int old = atomicAdd(&ws->done, 1);
      *sh_last = (old == NB - 1) ? 1 : 0;
    }
    __syncthreads();
    if (*sh_last && tid == 0) {
      __threadfence();
      float cls_s = 0.f, reg_s = 0.f, np_s = 0.f;
      for (int bb = 0; bb < NB; ++bb) {
        int np = ws->npos[bb];
        float pos_l = (np > 0) ? 5.f * ws->pos_sum[bb] / (float)np : 0.f;
        int M = ws->neg_cnt[bb];
        float kcnt = fminf((float)M, (float)KTOP);
        float neg_l = (kcnt > 0.f) ? ws->neg_sum[bb] / fmaxf(kcnt, 1.f) : 0.f;
        float reg_l = (np > 0) ? ws->reg_sum[bb] / (4.f * (float)np) : 0.f;
        cls_s += pos_l + neg_l;
        reg_s += reg_l;
        np_s += (float)np;
      }
      float cls = cls_s * 0.25f;
      float reg = reg_s * 0.25f;
      out[0] = cls + 0.5f * reg;
      out[1] = cls;
      out[2] = reg;
      out[3] = np_s;
    }
  }
}

// ---------------- fallback path (R4 kernels, proven correct) ----------------
__global__ void init_kernel(WsHeader* ws) {
  unsigned int* p = (unsigned int*)ws;
  const int nw = (int)(sizeof(WsHeader) / 4);
  for (int i = blockIdx.x * blockDim.x + threadIdx.x; i < nw; i += gridDim.x * blockDim.x)
    p[i] = 0u;
}

__global__ __launch_bounds__(256) void main_kernel(const float* __restrict__ pred,
                                                   const float* __restrict__ tgt,
                                                   WsHeader* __restrict__ ws,
                                                   unsigned int* __restrict__ keys) {
  __shared__ float gt[NG * 4];
  __shared__ unsigned int lhist[512];
  __shared__ float s_psum, s_rsum;
  __shared__ int s_np;
  const int b = blockIdx.y;
  const int tid = threadIdx.x;
  if (tid < NG * 4) gt[tid] = tgt[b * NG * 4 + tid];
  lhist[tid] = 0u; lhist[tid + 256] = 0u;
  if (tid == 0) { s_psum = 0.f; s_rsum = 0.f; s_np = 0; }
  __syncthreads();

  const int i = blockIdx.x * 256 + tid;
  int a = i % 3; int t = i / 3;
  int w = t % 48; t /= 48;
  int h = t % 48; int d = t / 48;
  const float cx = w * 4.f + 2.f, cy = h * 4.f + 2.f, cz = d * 4.f + 2.f;
  const float anch[3] = {5.f, 10.f, 20.f};
  const float an = anch[a];
  const float r1 = an * 0.5f;
  const float an3 = an * an * an;

  float best = -1.f; int arg = 0;
#pragma unroll
  for (int g = 0; g < NG; ++g) {
    float gx = gt[g * 4 + 0], gy = gt[g * 4 + 1], gz = gt[g * 4 + 2], gd = gt[g * 4 + 3];
    float r2 = gd * 0.5f;
    float ix = fmaxf(fminf(cx + r1, gx + r2) - fmaxf(cx - r1, gx - r2), 0.f);
    float iy = fmaxf(fminf(cy + r1, gy + r2) - fmaxf(cy - r1, gy - r2), 0.f);
    float iz = fmaxf(fminf(cz + r1, gz + r2) - fmaxf(cz - r1, gz - r2), 0.f);
    float iv = (ix * iy) * iz;
    float un = (an3 + gd * gd * gd) - iv;
    float iou = iv / (un + 1e-6f);
    if (iou > best) { best = iou; arg = g; }
  }
  const bool pos = best > 0.5f;
  const bool neg = best < 0.02f;
  const size_t base = (size_t)(b * NCELL + i) * 5;
  const float conf = pred[base];

  unsigned int key = 0u;
  if (neg) {
    key = f2key(conf);
    atomicAdd(&lhist[((tid & 1) << 8) | (key >> 24)], 1u);
  }
  keys[(size_t)b * NCELL + i] = key;

  if (pos) {
    float bce1 = fmaxf(conf, 0.f) - conf + log1pf(expf(-fabsf(conf)));
    float mgx = gt[arg * 4 + 0], mgy = gt[arg * 4 + 1], mgz = gt[arg * 4 + 2], mgd = gt[arg * 4 + 3];
    float t0 = (mgx - cx) / an, t1 = (mgy - cy) / an, t2 = (mgz - cz) / an;
    float t3 = logf(mgd / an);
    float d0 = pred[base + 1] - t0;
    float d1 = pred[base + 2] - t1;
    float d2 = pred[base + 3] - t2;
    float d3 = pred[base + 4] - t3;
    float rl = sl1(d0) + sl1(d1) + sl1(d2) + sl1(d3);
    atomicAdd(&s_psum, bce1);
    atomicAdd(&s_rsum, rl);
    atomicAdd(&s_np, 1);
  }
  __syncthreads();

  unsigned int c = lhist[tid] + lhist[tid + 256];
  if (c) atomicAdd(&ws->hist[b][blockIdx.x & (NREP - 1)][tid], c);
  if (tid == 0 && s_np > 0) {
    atomicAdd(&ws->pos_sum[b], s_psum);
    atomicAdd(&ws->reg_sum[b], s_rsum);
    atomicAdd(&ws->npos[b], s_np);
  }
}

__global__ __launch_bounds__(256) void compact_kernel(const unsigned int* __restrict__ keys,
                                                      WsHeader* __restrict__ ws,
                                                      unsigned int* __restrict__ bucket) {
  const int b = blockIdx.y;
  const int tid = threadIdx.x;
  __shared__ unsigned int A[256];
  __shared__ unsigned int cnts[256];
  __shared__ int sh_j, sh_base;

  unsigned int s = 0;
#pragma unroll
  for (int r = 0; r < NREP; ++r) s += ws->hist[b][r][tid];
  A[tid] = s;
  __syncthreads();
  for (int dlt = 1; dlt < 256; dlt <<= 1) {
    unsigned int v = (tid + dlt < 256) ? A[tid + dlt] : 0u;
    __syncthreads();
    A[tid] += v;
    __syncthreads();
  }
  const int M = (int)A[0];
  const bool ta = (M < KTOP);
  if (!ta && A[tid] >= (unsigned)KTOP && (tid == 255 || A[tid + 1] < (unsigned)KTOP))
    sh_j = tid;
  __syncthreads();
  const unsigned int jthr = ta ? 0u : (unsigned int)sh_j;
  if (tid == 0 && blockIdx.x == 0) {
    ws->neg_cnt[b] = M;
    ws->take_all[b] = ta ? 1 : 0;
    ws->prefix8[b] = (int)jthr;
    int above = (!ta && jthr < 255u) ? (int)A[jthr + 1] : 0;
    ws->k_rem[b] = ta ? 0 : (KTOP - above);
  }

  const uint4* k4 = (const uint4*)(keys + (size_t)b * NCELL);
  const int base4 = blockIdx.x * 1024;
  int cnt = 0;
#pragma unroll
  for (int it = 0; it < 4; ++it) {
    uint4 kk = k4[base4 + it * 256 + tid];
    cnt += (kk.x != 0u && (kk.x >> 24) >= jthr);
    cnt += (kk.y != 0u && (kk.y >> 24) >= jthr);
    cnt += (kk.z != 0u && (kk.z >> 24) >= jthr);
    cnt += (kk.w != 0u && (kk.w >> 24) >= jthr);
  }
  cnts[tid] = (unsigned int)cnt;
  __syncthreads();
  for (int dlt = 1; dlt < 256; dlt <<= 1) {
    unsigned int v = (tid >= dlt) ? cnts[tid - dlt] : 0u;
    __syncthreads();
    cnts[tid] += v;
    __syncthreads();
  }
  if (tid == 255) {
    int total = (int)cnts[255];
    sh_base = total ? atomicAdd(&ws->bucket_cnt[b][0], total) : 0;
  }
  __syncthreads();
  int off = sh_base + (int)cnts[tid] - cnt;
#pragma unroll
  for (int it = 0; it < 4; ++it) {
    uint4 kk = k4[base4 + it * 256 + tid];
    unsigned int kv;
    kv = kk.x; if (kv != 0u && (kv >> 24) >= jthr) { if (off < CAP) bucket[(size_t)b * CAP + off] = kv; ++off; }
    kv = kk.y; if (kv != 0u && (kv >> 24) >= jthr) { if (off < CAP) bucket[(size_t)b * CAP + off] = kv; ++off; }
    kv = kk.z; if (kv != 0u && (kv >> 24) >= jthr) { if (off < CAP) bucket[(size_t)b * CAP + off] = kv; ++off; }
    kv = kk.w; if (kv != 0u && (kv >> 24) >= jthr) { if (off < CAP) bucket[(size_t)b * CAP + off] = kv; ++off; }
  }
}

__global__ __launch_bounds__(1024) void final_kernel(const unsigned int* __restrict__ bucket,
                                                     WsHeader* __restrict__ ws,
                                                     float* __restrict__ out) {
  const int b = blockIdx.x;
  const int tid = threadIdx.x;
  __shared__ unsigned int skeys[LCAP];
  __shared__ unsigned int h[256];
  __shared__ unsigned int A[256];
  __shared__ int sh_j;
  __shared__ float wred[16];
  __shared__ int sh_last;

  int m = ws->bucket_cnt[b][0]; if (m > CAP) m = CAP;
  const bool ta = ws->take_all[b] != 0;
  const unsigned int* kb = bucket + (size_t)b * CAP;
  const bool useLds = (m <= LCAP);
  if (useLds)
    for (int i = tid; i < m; i += 1024) skeys[i] = kb[i];
  __syncthreads();

  unsigned int T = 0u;
  int k = 0;
  if (!ta) {
    unsigned int P = ((unsigned int)ws->prefix8[b]) << 24;
    k = ws->k_rem[b];
    for (int pass = 1; pass < 4; ++pass) {
      const int sh = 24 - 8 * pass;
      const unsigned int hiMask = 0xFFFFFFFFu << (sh + 8);
      if (tid < 256) h[tid] = 0u;
      __syncthreads();
      for (int i = tid; i < m; i += 1024) {
        unsigned int kv = useLds ? skeys[i] : kb[i];
        if (((kv ^ P) & hiMask) == 0u) atomicAdd(&h[(kv >> sh) & 255u], 1u);
      }
      __syncthreads();
      if (tid < 256) A[tid] = h[tid];
      __syncthreads();
      for (int dlt = 1; dlt < 256; dlt <<= 1) {
        unsigned int v = (tid < 256 && tid + dlt < 256) ? A[tid + dlt] : 0u;
        __syncthreads();
        if (tid < 256) A[tid] += v;
        __syncthreads();
      }
      if (tid < 256 && A[tid] >= (unsigned)k && (tid == 255 || A[tid + 1] < (unsigned)k))
        sh_j = tid;
      __syncthreads();
      const int j = sh_j;
      k -= (j == 255) ? 0 : (int)A[j + 1];
      P |= ((unsigned int)j) << sh;
      __syncthreads();
    }
    T = P;
  }

  float v = 0.f;
  for (int i = tid; i < m; i += 1024) {
    unsigned int kv = useLds ? skeys[i] : kb[i];
    if (ta || kv > T) v += softplus0(key2f(kv));
  }
  for (int o = 32; o > 0; o >>= 1) v += __shfl_down(v, o);
  if ((tid & 63) == 0) wred[tid >> 6] = v;
  __syncthreads();
  if (tid == 0) {
    float sum = 0.f;
#pragma unroll
    for (int wv = 0; wv < 16; ++wv) sum += wred[wv];
    if (!ta) sum += (float)k * softplus0(key2f(T));
    ws->neg_sum[b] = sum;
    __threadfence();
    int old = atomicAdd(&ws->done, 1);
    sh_last = (old == NB - 1) ? 1 : 0;
  }
  __syncthreads();
  if (sh_last && tid == 0) {
    __threadfence();
    float cls_s = 0.f, reg_s = 0.f, np_s = 0.f;
    for (int bb = 0; bb < NB; ++bb) {
      int np = ws->npos[bb];
      float pos_l = (np > 0) ? 5.f * ws->pos_sum[bb] / (float)np : 0.f;
      int M = ws->neg_cnt[bb];
      float kcnt = fminf((float)M, (float)KTOP);
      float neg_l = (kcnt > 0.f) ? ws->neg_sum[bb] / fmaxf(kcnt, 1.f) : 0.f;
      float reg_l = (np > 0) ? ws->reg_sum[bb] / (4.f * (float)np) : 0.f;
      cls_s += pos_l + neg_l;
      reg_s += reg_l;
      np_s += (float)np;
    }
    float cls = cls_s * 0.25f;
    float reg = reg_s * 0.25f;
    out[0] = cls + 0.5f * reg;
    out[1] = cls;
    out[2] = reg;
    out[3] = np_s;
  }
}

extern "C" void kernel_launch(void* const* d_in, const int* in_sizes, int n_in,
                              void* d_out, int out_size, void* d_ws, size_t ws_size,
                              hipStream_t stream) {
  const float* pred = (const float*)d_in[0];
  const float* tgt  = (const float*)d_in[1];
  WsHeader* ws = (WsHeader*)d_ws;
  char* base = (char*)d_ws + ((sizeof(WsHeader) + 255) / 256) * 256;
  unsigned int* keys = (unsigned int*)base;
  unsigned int* bucket = (unsigned int*)(base + (size_t)NB * NCELL * 4);
  float* out = (float*)d_out;

  void* args[] = {(void*)&pred, (void*)&tgt, (void*)&ws, (void*)&keys, (void*)&bucket, (void*)&out};
  hipError_t err = hipLaunchCooperativeKernel((void*)fused_kernel, dim3(GRID), dim3(256),
                                              args, 0, stream);
  if (err != hipSuccess) {
    // fallback: proven 4-kernel path
    hipLaunchKernelGGL(init_kernel, dim3(16), dim3(256), 0, stream, ws);
    hipLaunchKernelGGL(main_kernel, dim3(NBLK, NB), dim3(256), 0, stream, pred, tgt, ws, keys);
    hipLaunchKernelGGL(compact_kernel, dim3(NBLK / 16, NB), dim3(256), 0, stream, keys, ws, bucket);
    hipLaunchKernelGGL(final_kernel, dim3(NB), dim3(1024), 0, stream, bucket, ws, out);
  }
}

// Round 6
// 150.496 us; speedup vs baseline: 4.5294x; 4.5294x over previous
//
#include <hip/hip_runtime.h>
#include <cstdint>
#include <cstddef>

#define NB 4
#define NG 8
#define NCELL 331776   // 48*48*48*3
#define NTILE 1296     // 256-cell tiles per batch
#define KTOP 800
#define NREP 8         // global histogram replicas to spread atomic traffic
#define CAP 16384      // per-batch candidate buffer capacity (expected ~7.4k)
#define LCAP 12288     // candidates cached in LDS when m <= LCAP (48 KB)
#define CBLK 81        // compact blocks per batch (81 * 4096 = NCELL)

struct WsHeader {
  float pos_sum[NB];
  float reg_sum[NB];
  int   npos[NB];
  int   neg_cnt[NB];
  float neg_sum[NB];
  int   done_b[NB];             // per-batch compact completion counter
  int   done;                   // batch-finisher completion counter (combine)
  int   bucket_cnt[NB][16];     // one cacheline per batch
  unsigned int hist[NB][NREP][256];
};

__device__ __forceinline__ float softplus0(float x) {
  // _bce_logits(x, 0) = max(x,0) + log1p(exp(-|x|))
  return fmaxf(x, 0.f) + log1pf(expf(-fabsf(x)));
}
__device__ __forceinline__ unsigned int f2key(float f) {
  unsigned int u = __float_as_uint(f);
  return (u & 0x80000000u) ? ~u : (u | 0x80000000u);
}
__device__ __forceinline__ float key2f(unsigned int k) {
  unsigned int u = (k & 0x80000000u) ? (k & 0x7fffffffu) : ~k;
  return __uint_as_float(u);
}
__device__ __forceinline__ float sl1(float x) {
  float ax = fabsf(x);
  return ax < 1.f ? 0.5f * x * x : ax - 0.5f;
}

__global__ void init_kernel(WsHeader* ws) {
  unsigned int* p = (unsigned int*)ws;
  const int nw = (int)(sizeof(WsHeader) / 4);
  for (int i = blockIdx.x * blockDim.x + threadIdx.x; i < nw; i += gridDim.x * blockDim.x)
    p[i] = 0u;
}

// Per-cell loss terms + dense key write + top-byte histogram.
// pred staged through LDS via coalesced float4 loads (stride-5 dword LDS reads
// are 2-way bank-aliased = free; replica stride 257 de-aliases hist banks).
__global__ __launch_bounds__(256) void main_kernel(const float* __restrict__ pred,
                                                   const float* __restrict__ tgt,
                                                   WsHeader* __restrict__ ws,
                                                   unsigned int* __restrict__ keys) {
  __shared__ __align__(16) float ld[1280];     // 256 cells x 5 floats
  __shared__ float gt[NG * 4];
  __shared__ unsigned int lhist[4 * 257];      // 4 replicas, stride 257
  __shared__ float s_psum, s_rsum;
  __shared__ int s_np;
  const int b = blockIdx.y;
  const int tile = blockIdx.x;
  const int tid = threadIdx.x;

  if (tid < NG * 4) gt[tid] = tgt[b * NG * 4 + tid];
  for (int e = tid; e < 4 * 257; e += 256) lhist[e] = 0u;
  if (tid == 0) { s_psum = 0.f; s_rsum = 0.f; s_np = 0; }

  const float4* p4 = (const float4*)(pred + ((size_t)b * NCELL + (size_t)tile * 256) * 5);
  float4* ld4 = (float4*)ld;
  ld4[tid] = p4[tid];
  if (tid < 64) ld4[256 + tid] = p4[256 + tid];
  __syncthreads();

  const int i = tile * 256 + tid;
  int a = i % 3; int t = i / 3;
  int w = t % 48; t /= 48;
  int h = t % 48; int d = t / 48;
  const float cx = w * 4.f + 2.f, cy = h * 4.f + 2.f, cz = d * 4.f + 2.f;
  const float anch[3] = {5.f, 10.f, 20.f};
  const float an = anch[a];
  const float r1 = an * 0.5f;
  const float an3 = an * an * an;

  float best = -1.f; int arg = 0;
#pragma unroll
  for (int g = 0; g < NG; ++g) {
    float gx = gt[g * 4 + 0], gy = gt[g * 4 + 1], gz = gt[g * 4 + 2], gd = gt[g * 4 + 3];
    float r2 = gd * 0.5f;
    float ix = fmaxf(fminf(cx + r1, gx + r2) - fmaxf(cx - r1, gx - r2), 0.f);
    float iy = fmaxf(fminf(cy + r1, gy + r2) - fmaxf(cy - r1, gy - r2), 0.f);
    float iz = fmaxf(fminf(cz + r1, gz + r2) - fmaxf(cz - r1, gz - r2), 0.f);
    float iv = (ix * iy) * iz;
    float un = (an3 + gd * gd * gd) - iv;
    float iou = iv / (un + 1e-6f);
    if (iou > best) { best = iou; arg = g; }   // strict > == first-argmax
  }
  const bool pos = best > 0.5f;
  const bool neg = best < 0.02f;
  const float conf = ld[tid * 5];

  unsigned int key = 0u;   // sentinel: -NaN bit pattern, unreachable as real key
  if (neg) {
    key = f2key(conf);
    atomicAdd(&lhist[(tid & 3) * 257 + (key >> 24)], 1u);
  }
  keys[(size_t)b * NCELL + i] = key;

  if (pos) {
    float bce1 = fmaxf(conf, 0.f) - conf + log1pf(expf(-fabsf(conf)));
    float mgx = gt[arg * 4 + 0], mgy = gt[arg * 4 + 1], mgz = gt[arg * 4 + 2], mgd = gt[arg * 4 + 3];
    float t0 = (mgx - cx) / an, t1 = (mgy - cy) / an, t2 = (mgz - cz) / an;
    float t3 = logf(mgd / an);
    float d0 = ld[tid * 5 + 1] - t0;
    float d1 = ld[tid * 5 + 2] - t1;
    float d2 = ld[tid * 5 + 3] - t2;
    float d3 = ld[tid * 5 + 4] - t3;
    float rl = sl1(d0) + sl1(d1) + sl1(d2) + sl1(d3);
    atomicAdd(&s_psum, bce1);
    atomicAdd(&s_rsum, rl);
    atomicAdd(&s_np, 1);
  }
  __syncthreads();

  unsigned int c = lhist[tid] + lhist[257 + tid] + lhist[514 + tid] + lhist[771 + tid];
  if (c) atomicAdd(&ws->hist[b][blockIdx.x & (NREP - 1)][tid], c);
  if (tid == 0 && s_np > 0) {        // rare: fire-and-forget, most blocks skip
    atomicAdd(&ws->pos_sum[b], s_psum);
    atomicAdd(&ws->reg_sum[b], s_rsum);
    atomicAdd(&ws->npos[b], s_np);
  }
}

// Merged compact + final: every block finds the top-byte threshold bucket j
// (redundantly, from the global histogram) and compacts its 4096-key slice.
// The LAST block per batch (done_b counter) then does the exact top-K select
// over the compacted candidates; the last batch-finisher does the combine.
__global__ __launch_bounds__(256) void compact_final_kernel(const unsigned int* __restrict__ keys,
                                                            WsHeader* __restrict__ ws,
                                                            unsigned int* __restrict__ bucket,
                                                            float* __restrict__ out) {
  const int b = blockIdx.y;
  const int tl = blockIdx.x;
  const int tid = threadIdx.x;
  __shared__ unsigned int skeys[LCAP];
  __shared__ unsigned int sA[256];
  __shared__ unsigned int sB[256];
  __shared__ int sh_j, sh_base, sh_fin, sh_fin2;
  __shared__ float wred[4];

  // ---- threshold bucket from replica-summed histogram ----
  unsigned int s = 0;
#pragma unroll
  for (int r = 0; r < NREP; ++r) s += ws->hist[b][r][tid];
  sA[tid] = s;
  __syncthreads();
  for (int dlt = 1; dlt < 256; dlt <<= 1) {   // inclusive suffix scan
    unsigned int v = (tid + dlt < 256) ? sA[tid + dlt] : 0u;
    __syncthreads();
    sA[tid] += v;
    __syncthreads();
  }
  const int M = (int)sA[0];
  const bool ta = (M < KTOP);
  if (!ta && sA[tid] >= (unsigned)KTOP && (tid == 255 || sA[tid + 1] < (unsigned)KTOP))
    sh_j = tid;
  __syncthreads();
  const unsigned int jthr = ta ? 0u : (unsigned int)sh_j;
  const int krem0 = ta ? 0 : (KTOP - ((jthr < 255u) ? (int)sA[jthr + 1] : 0));

  // ---- compact this block's slice ----
  const uint4* k4 = (const uint4*)(keys + (size_t)b * NCELL);
  const int base4 = tl * 1024;
  int cnt = 0;
#pragma unroll
  for (int it = 0; it < 4; ++it) {
    uint4 kk = k4[base4 + it * 256 + tid];
    cnt += (kk.x != 0u && (kk.x >> 24) >= jthr);
    cnt += (kk.y != 0u && (kk.y >> 24) >= jthr);
    cnt += (kk.z != 0u && (kk.z >> 24) >= jthr);
    cnt += (kk.w != 0u && (kk.w >> 24) >= jthr);
  }
  sB[tid] = (unsigned int)cnt;
  __syncthreads();
  for (int dlt = 1; dlt < 256; dlt <<= 1) {   // inclusive prefix scan
    unsigned int v = (tid >= dlt) ? sB[tid - dlt] : 0u;
    __syncthreads();
    sB[tid] += v;
    __syncthreads();
  }
  if (tid == 255) {
    int total = (int)sB[255];
    sh_base = total ? atomicAdd(&ws->bucket_cnt[b][0], total) : 0;
  }
  __syncthreads();
  int off = sh_base + (int)sB[tid] - cnt;
#pragma unroll
  for (int it = 0; it < 4; ++it) {
    uint4 kk = k4[base4 + it * 256 + tid];
    unsigned int kv;
    kv = kk.x; if (kv != 0u && (kv >> 24) >= jthr) { if (off < CAP) bucket[(size_t)b * CAP + off] = kv; ++off; }
    kv = kk.y; if (kv != 0u && (kv >> 24) >= jthr) { if (off < CAP) bucket[(size_t)b * CAP + off] = kv; ++off; }
    kv = kk.z; if (kv != 0u && (kv >> 24) >= jthr) { if (off < CAP) bucket[(size_t)b * CAP + off] = kv; ++off; }
    kv = kk.w; if (kv != 0u && (kv >> 24) >= jthr) { if (off < CAP) bucket[(size_t)b * CAP + off] = kv; ++off; }
  }

  // ---- arrive; last block of this batch proceeds to the final select ----
  __threadfence();
  if (tid == 0) {
    int old = atomicAdd(&ws->done_b[b], 1);
    sh_fin = (old == CBLK - 1) ? 1 : 0;
  }
  __syncthreads();
  if (!sh_fin) return;
  __threadfence();   // acquire: all 81 blocks' bucket writes now visible

  int m = ws->bucket_cnt[b][0]; if (m > CAP) m = CAP;
  const unsigned int* kb = bucket + (size_t)b * CAP;
  const bool useLds = (m <= LCAP);
  if (useLds)
    for (int i = tid; i < m; i += 256) skeys[i] = kb[i];
  __syncthreads();

  unsigned int T = 0u;
  int k = 0;
  if (!ta) {
    unsigned int P = jthr << 24;
    k = krem0;
    for (int pass = 1; pass < 4; ++pass) {
      const int sh = 24 - 8 * pass;
      const unsigned int hiMask = 0xFFFFFFFFu << (sh + 8);
      sA[tid] = 0u;
      __syncthreads();
      for (int i = tid; i < m; i += 256) {
        unsigned int kv = useLds ? skeys[i] : kb[i];
        if (((kv ^ P) & hiMask) == 0u) atomicAdd(&sA[(kv >> sh) & 255u], 1u);
      }
      __syncthreads();
      sB[tid] = sA[tid];
      __syncthreads();
      for (int dlt = 1; dlt < 256; dlt <<= 1) {
        unsigned int v = (tid + dlt < 256) ? sB[tid + dlt] : 0u;
        __syncthreads();
        sB[tid] += v;
        __syncthreads();
      }
      if (sB[tid] >= (unsigned)k && (tid == 255 || sB[tid + 1] < (unsigned)k))
        sh_j = tid;
      __syncthreads();
      const int j = sh_j;
      k -= (j == 255) ? 0 : (int)sB[j + 1];   // remove strictly-greater bins
      P |= ((unsigned int)j) << sh;
      __syncthreads();
    }
    T = P;   // exact threshold key; k = #ties to take at T
  }

  float v = 0.f;
  for (int i = tid; i < m; i += 256) {
    unsigned int kv = useLds ? skeys[i] : kb[i];
    if (ta || kv > T) v += softplus0(key2f(kv));
  }
  for (int o = 32; o > 0; o >>= 1) v += __shfl_down(v, o);
  if ((tid & 63) == 0) wred[tid >> 6] = v;
  __syncthreads();
  if (tid == 0) {
    float sum = wred[0] + wred[1] + wred[2] + wred[3];
    if (!ta) sum += (float)k * softplus0(key2f(T));
    ws->neg_sum[b] = sum;
    ws->neg_cnt[b] = M;
    __threadfence();
    int old = atomicAdd(&ws->done, 1);
    sh_fin2 = (old == NB - 1) ? 1 : 0;
  }
  __syncthreads();
  if (sh_fin2 && tid == 0) {
    __threadfence();
    float cls_s = 0.f, reg_s = 0.f, np_s = 0.f;
    for (int bb = 0; bb < NB; ++bb) {
      int np = ws->npos[bb];
      float pos_l = (np > 0) ? 5.f * ws->pos_sum[bb] / (float)np : 0.f;
      int Mb = ws->neg_cnt[bb];
      float kcnt = fminf((float)Mb, (float)KTOP);
      float neg_l = (kcnt > 0.f) ? ws->neg_sum[bb] / fmaxf(kcnt, 1.f) : 0.f;
      float reg_l = (np > 0) ? ws->reg_sum[bb] / (4.f * (float)np) : 0.f;
      cls_s += pos_l + neg_l;
      reg_s += reg_l;
      np_s += (float)np;
    }
    float cls = cls_s * 0.25f;
    float reg = reg_s * 0.25f;
    out[0] = cls + 0.5f * reg;
    out[1] = cls;
    out[2] = reg;
    out[3] = np_s;
  }
}

extern "C" void kernel_launch(void* const* d_in, const int* in_sizes, int n_in,
                              void* d_out, int out_size, void* d_ws, size_t ws_size,
                              hipStream_t stream) {
  const float* pred = (const float*)d_in[0];
  const float* tgt  = (const float*)d_in[1];
  WsHeader* ws = (WsHeader*)d_ws;
  char* base = (char*)d_ws + ((sizeof(WsHeader) + 255) / 256) * 256;
  unsigned int* keys = (unsigned int*)base;
  unsigned int* bucket = (unsigned int*)(base + (size_t)NB * NCELL * 4);
  float* out = (float*)d_out;

  hipLaunchKernelGGL(init_kernel, dim3(8), dim3(256), 0, stream, ws);
  hipLaunchKernelGGL(main_kernel, dim3(NTILE, NB), dim3(256), 0, stream, pred, tgt, ws, keys);
  hipLaunchKernelGGL(compact_final_kernel, dim3(CBLK, NB), dim3(256), 0, stream, keys, ws, bucket, out);
}